// Round 1
// baseline (726.135 us; speedup 1.0000x reference)
//
#include <hip/hip_runtime.h>

#define DD 64
#define HH 256
#define WW 256
#define NN (DD*HH*WW)   // 4194304
#define GHS 4096        // global hash slots (power of 2)
#define LHS 256         // per-block LDS hash slots (== blockDim)

// ---------------- lock-free union-find (atomicMin style) ----------------
__device__ __forceinline__ int ufind(int* P, int x){
  int p = P[x];
  while (p != x){ x = p; p = P[x]; }
  return x;
}

__device__ __forceinline__ void uunion(int* P, int a, int b){
  while (true){
    a = ufind(P, a);
    b = ufind(P, b);
    if (a == b) return;
    if (a < b){ int t = a; a = b; b = t; }   // ensure a > b
    int old = atomicMin(&P[a], b);
    if (old == a) return;                     // we linked root a -> b
    a = old;                                  // someone else linked a; continue from old
  }
}

// ---------------- kernels ----------------
__global__ void k_init(const float* __restrict__ in, int* __restrict__ parent,
                       int* __restrict__ hkey, int* __restrict__ harea,
                       int* __restrict__ hper){
  int i = blockIdx.x * blockDim.x + threadIdx.x;
  if (i < NN) parent[i] = (in[i] > 0.5f) ? i : -1;
  if (i < GHS){ hkey[i] = -1; harea[i] = 0; hper[i] = 0; }
}

__global__ void k_merge(int* __restrict__ parent){
  int i = blockIdx.x * blockDim.x + threadIdx.x;
  if (i >= NN) return;
  if (parent[i] < 0) return;
  int x = i & 255, y = (i >> 8) & 255, z = i >> 16;
  const int offs[13][3] = {
    {-1,-1,-1},{-1,-1,0},{-1,-1,1},
    {-1, 0,-1},{-1, 0,0},{-1, 0,1},
    {-1, 1,-1},{-1, 1,0},{-1, 1,1},
    { 0,-1,-1},{ 0,-1,0},{ 0,-1,1},
    { 0, 0,-1}};
  #pragma unroll
  for (int k = 0; k < 13; k++){
    int zz = z + offs[k][0];
    int yy = y + offs[k][1];
    int xx = x + offs[k][2];
    if (zz < 0 || yy < 0 || yy >= HH || xx < 0 || xx >= WW) continue; // zz<=z so zz<DD always
    int j = (zz << 16) | (yy << 8) | xx;
    if (parent[j] >= 0) uunion(parent, i, j);
  }
}

__global__ void k_flatten(int* __restrict__ parent){
  int i = blockIdx.x * blockDim.x + threadIdx.x;
  if (i >= NN) return;
  if (parent[i] < 0) return;
  parent[i] = ufind(parent, i);
}

__device__ __forceinline__ void ghash_add(int* hkey, int* harea, int* hper,
                                          int key, int a, int p){
  unsigned h = ((unsigned)key * 2654435761u) >> 20;   // top 12 bits -> [0,4096)
  while (true){
    int old = atomicCAS(&hkey[h], -1, key);
    if (old == -1 || old == key){
      atomicAdd(&harea[h], a);
      if (p) atomicAdd(&hper[h], p);
      return;
    }
    h = (h + 1) & (GHS - 1);
  }
}

__global__ void k_accum(const int* __restrict__ parent, int* __restrict__ hkey,
                        int* __restrict__ harea, int* __restrict__ hper){
  __shared__ int sk[LHS];
  __shared__ int sa[LHS];
  __shared__ int sp[LHS];
  int t = threadIdx.x;
  sk[t] = -1; sa[t] = 0; sp[t] = 0;   // blockDim.x == LHS == 256
  __syncthreads();

  int i = blockIdx.x * blockDim.x + t;
  if (i < NN){
    int r = parent[i];
    if (r >= 0){
      int x = i & 255, y = (i >> 8) & 255, z = i >> 16;
      // inner boundary, 18-neighborhood (|dz|+|dy|+|dx| nonzeros in {1,2}), reflect pad=1
      const int offs[18][3] = {
        {-1,-1,0},{-1,0,-1},{-1,0,0},{-1,0,1},{-1,1,0},
        {0,-1,-1},{0,-1,0},{0,-1,1},
        {0,0,-1},          {0,0,1},
        {0,1,-1},{0,1,0},{0,1,1},
        {1,-1,0},{1,0,-1},{1,0,0},{1,0,1},{1,1,0}};
      bool all_fg = true;
      #pragma unroll
      for (int k = 0; k < 18; k++){
        int zz = z + offs[k][0]; zz = (zz < 0) ? 1 : ((zz >= DD) ? (DD - 2) : zz);
        int yy = y + offs[k][1]; yy = (yy < 0) ? 1 : ((yy >= HH) ? (HH - 2) : yy);
        int xx = x + offs[k][2]; xx = (xx < 0) ? 1 : ((xx >= WW) ? (WW - 2) : xx);
        int j = (zz << 16) | (yy << 8) | xx;
        if (parent[j] < 0){ all_fg = false; break; }
      }
      int bnd = all_fg ? 0 : 1;

      // LDS hash insert (distinct roots per block <= 256 slots, no livelock)
      unsigned h = ((unsigned)r * 2654435761u) >> 24;   // top 8 bits -> [0,256)
      while (true){
        int old = atomicCAS(&sk[h], -1, r);
        if (old == -1 || old == r){
          atomicAdd(&sa[h], 1);
          if (bnd) atomicAdd(&sp[h], 1);
          break;
        }
        h = (h + 1) & (LHS - 1);
      }
    }
  }
  __syncthreads();
  int key = sk[t];
  if (key >= 0) ghash_add(hkey, harea, hper, key, sa[t], sp[t]);
}

__global__ void k_final(const int* __restrict__ hkey, const int* __restrict__ harea,
                        const int* __restrict__ hper, float* __restrict__ out){
  __shared__ float ssum[256];
  int t = threadIdx.x;
  float s = 0.0f;
  for (int j = t; j < GHS; j += 256){
    if (hkey[j] >= 0){
      float a = (float)harea[j];
      float p = (float)hper[j];
      s += 12.566370614359172f * a / (p * p + 1e-5f);   // 4*pi*A/(P^2+EPS), fp32 like ref
    }
  }
  ssum[t] = s;
  __syncthreads();
  for (int w = 128; w > 0; w >>= 1){
    if (t < w) ssum[t] += ssum[t + w];
    __syncthreads();
  }
  if (t == 0){
    float comp = ssum[0] / 64.0f;        // sum(per_label) / D
    out[0] = 1.0f / (comp + 1e-5f);      // 1/(comp + EPS)
  }
}

// ---------------- launcher ----------------
extern "C" void kernel_launch(void* const* d_in, const int* in_sizes, int n_in,
                              void* d_out, int out_size, void* d_ws, size_t ws_size,
                              hipStream_t stream){
  const float* y = (const float*)d_in[0];
  int* parent = (int*)d_ws;           // NN int32 = 16 MiB
  int* hkey   = parent + NN;          // GHS
  int* harea  = hkey + GHS;           // GHS
  int* hper   = harea + GHS;          // GHS
  float* out  = (float*)d_out;

  dim3 blk(256);
  dim3 grd((NN + 255) / 256);
  hipLaunchKernelGGL(k_init,    grd, blk, 0, stream, y, parent, hkey, harea, hper);
  hipLaunchKernelGGL(k_merge,   grd, blk, 0, stream, parent);
  hipLaunchKernelGGL(k_flatten, grd, blk, 0, stream, parent);
  hipLaunchKernelGGL(k_accum,   grd, blk, 0, stream, parent, hkey, harea, hper);
  hipLaunchKernelGGL(k_final, dim3(1), blk, 0, stream, hkey, harea, hper, out);
}

// Round 2
// 605.847 us; speedup vs baseline: 1.1985x; 1.1985x over previous
//
#include <hip/hip_runtime.h>

#define DD 64
#define HH 256
#define WW 256
#define NN (DD*HH*WW)   // 4194304
#define GHS 4096        // global hash slots (power of 2)
#define LHS 256         // per-block LDS hash slots (== blockDim)

// tile for local CCL phase
#define TZ 8
#define TY 32
#define TX 32
#define TVOX (TZ*TY*TX) // 8192 -> 32 KB LDS

// backward 26-neighborhood offsets (13): all (dz,dy,dx) lexicographically < 0
#define OFFS_LIST \
  {-1,-1,-1},{-1,-1,0},{-1,-1,1}, \
  {-1, 0,-1},{-1, 0,0},{-1, 0,1}, \
  {-1, 1,-1},{-1, 1,0},{-1, 1,1}, \
  { 0,-1,-1},{ 0,-1,0},{ 0,-1,1}, \
  { 0, 0,-1}

// ---------------- union-find with path halving ----------------
// Works on LDS or global pointers. Safety: every write stores a value that was
// an ancestor at read time and preserves P[x] <= x, so connectivity is never
// lost and load-bearing atomicMin root-links (old==a) cannot be clobbered.
__device__ __forceinline__ int ufind(int* P, int x){
  int p = P[x];
  while (p != x){
    int gp = P[p];
    if (gp != p) P[x] = gp;   // path halving
    x = gp;
    p = P[x];
  }
  return x;
}

__device__ __forceinline__ void uunion(int* P, int a, int b){
  while (true){
    a = ufind(P, a);
    b = ufind(P, b);
    if (a == b) return;
    if (a < b){ int t = a; a = b; b = t; }   // ensure a > b (link big -> small)
    int old = atomicMin(&P[a], b);
    if (old == a) return;                     // we linked root a -> b
    a = old;                                  // a already had a parent; merge that chain
  }
}

// ---------------- phase A: fused init + tile-local CCL in LDS ----------------
__global__ __launch_bounds__(256) void k_local(const float* __restrict__ in,
                                               int* __restrict__ parent,
                                               int* __restrict__ hkey,
                                               int* __restrict__ harea,
                                               int* __restrict__ hper){
  __shared__ int sl[TVOX];
  const int t = threadIdx.x;
  const int b = blockIdx.x;           // 512 tiles: 8 x 8 x 8
  const int z0 = (b >> 6) * TZ;
  const int y0 = ((b >> 3) & 7) * TY;
  const int x0 = (b & 7) * TX;

  // init global hash (first 16 blocks)
  if (b < GHS / 256){ int j = b * 256 + t; hkey[j] = -1; harea[j] = 0; hper[j] = 0; }

  // init local labels from input
  for (int v = t; v < TVOX; v += 256){
    int lz = v >> 10, ly = (v >> 5) & 31, lx = v & 31;
    int gi = ((z0 + lz) << 16) | ((y0 + ly) << 8) | (x0 + lx);
    sl[v] = (in[gi] > 0.5f) ? v : -1;
  }
  __syncthreads();

  // local unions over backward neighbors (in-tile only)
  const int offs[13][3] = { OFFS_LIST };
  for (int v = t; v < TVOX; v += 256){
    if (sl[v] < 0) continue;
    int lz = v >> 10, ly = (v >> 5) & 31, lx = v & 31;
    #pragma unroll
    for (int k = 0; k < 13; k++){
      int zz = lz + offs[k][0];
      int yy = ly + offs[k][1];
      int xx = lx + offs[k][2];
      if (zz < 0 || yy < 0 || yy >= TY || xx < 0 || xx >= TX) continue;
      int u = (zz << 10) | (yy << 5) | xx;
      if (sl[u] >= 0) uunion(sl, v, u);
    }
  }
  __syncthreads();

  // write parent[] with tile-local roots converted to global indices.
  // local flat order is lexicographic in (z,y,x) like the global order, so
  // min-local-root == min-global-index within the tile (preserves invariant).
  for (int v = t; v < TVOX; v += 256){
    int lz = v >> 10, ly = (v >> 5) & 31, lx = v & 31;
    int gi = ((z0 + lz) << 16) | ((y0 + ly) << 8) | (x0 + lx);
    if (sl[v] < 0){ parent[gi] = -1; continue; }
    int r = ufind(sl, v);
    int rz = r >> 10, ry = (r >> 5) & 31, rx = r & 31;
    parent[gi] = ((z0 + rz) << 16) | ((y0 + ry) << 8) | (x0 + rx);
  }
}

// ---------------- phase B: cross-tile unions only ----------------
__global__ void k_cross(int* __restrict__ parent){
  int i = blockIdx.x * blockDim.x + threadIdx.x;
  if (i >= NN) return;
  int x = i & 255, y = (i >> 8) & 255, z = i >> 16;
  int lx = x & 31, ly = y & 31, lz = z & 7;
  // interior voxels cannot have a cross-tile backward neighbor
  // (backward offsets: dz in {-1,0}; dy,dx in {-1,0,1})
  if (lz != 0 && ly != 0 && ly != 31 && lx != 0 && lx != 31) return;
  if (parent[i] < 0) return;
  const int offs[13][3] = { OFFS_LIST };
  #pragma unroll
  for (int k = 0; k < 13; k++){
    int zz = z + offs[k][0];
    int yy = y + offs[k][1];
    int xx = x + offs[k][2];
    if (zz < 0 || yy < 0 || yy >= HH || xx < 0 || xx >= WW) continue;
    // skip in-tile pairs (already merged in phase A)
    if ((zz >> 3) == (z >> 3) && (yy >> 5) == (y >> 5) && (xx >> 5) == (x >> 5)) continue;
    int j = (zz << 16) | (yy << 8) | xx;
    if (parent[j] >= 0) uunion(parent, i, j);
  }
}

// ---------------- phase C: flatten to roots ----------------
__global__ void k_flatten(int* __restrict__ parent){
  int i = blockIdx.x * blockDim.x + threadIdx.x;
  if (i >= NN) return;
  if (parent[i] < 0) return;
  parent[i] = ufind(parent, i);
}

// ---------------- phase D: per-component area/perimeter ----------------
__device__ __forceinline__ void ghash_add(int* hkey, int* harea, int* hper,
                                          int key, int a, int p){
  unsigned h = ((unsigned)key * 2654435761u) >> 20;   // top 12 bits -> [0,4096)
  while (true){
    int old = atomicCAS(&hkey[h], -1, key);
    if (old == -1 || old == key){
      atomicAdd(&harea[h], a);
      if (p) atomicAdd(&hper[h], p);
      return;
    }
    h = (h + 1) & (GHS - 1);
  }
}

__global__ void k_accum(const int* __restrict__ parent, int* __restrict__ hkey,
                        int* __restrict__ harea, int* __restrict__ hper){
  __shared__ int sk[LHS];
  __shared__ int sa[LHS];
  __shared__ int sp[LHS];
  int t = threadIdx.x;
  sk[t] = -1; sa[t] = 0; sp[t] = 0;
  __syncthreads();

  int i = blockIdx.x * blockDim.x + t;
  if (i < NN){
    int r = parent[i];
    if (r >= 0){
      int x = i & 255, y = (i >> 8) & 255, z = i >> 16;
      // inner boundary, 18-neighborhood, reflect pad=1
      const int offs[18][3] = {
        {-1,-1,0},{-1,0,-1},{-1,0,0},{-1,0,1},{-1,1,0},
        {0,-1,-1},{0,-1,0},{0,-1,1},
        {0,0,-1},          {0,0,1},
        {0,1,-1},{0,1,0},{0,1,1},
        {1,-1,0},{1,0,-1},{1,0,0},{1,0,1},{1,1,0}};
      bool all_fg = true;
      #pragma unroll
      for (int k = 0; k < 18; k++){
        int zz = z + offs[k][0]; zz = (zz < 0) ? 1 : ((zz >= DD) ? (DD - 2) : zz);
        int yy = y + offs[k][1]; yy = (yy < 0) ? 1 : ((yy >= HH) ? (HH - 2) : yy);
        int xx = x + offs[k][2]; xx = (xx < 0) ? 1 : ((xx >= WW) ? (WW - 2) : xx);
        int j = (zz << 16) | (yy << 8) | xx;
        if (parent[j] < 0){ all_fg = false; break; }
      }
      int bnd = all_fg ? 0 : 1;

      // LDS hash insert (distinct roots per block <= 256 slots, no livelock)
      unsigned h = ((unsigned)r * 2654435761u) >> 24;
      while (true){
        int old = atomicCAS(&sk[h], -1, r);
        if (old == -1 || old == r){
          atomicAdd(&sa[h], 1);
          if (bnd) atomicAdd(&sp[h], 1);
          break;
        }
        h = (h + 1) & (LHS - 1);
      }
    }
  }
  __syncthreads();
  int key = sk[t];
  if (key >= 0) ghash_add(hkey, harea, hper, key, sa[t], sp[t]);
}

// ---------------- phase E: final reduction ----------------
__global__ void k_final(const int* __restrict__ hkey, const int* __restrict__ harea,
                        const int* __restrict__ hper, float* __restrict__ out){
  __shared__ float ssum[256];
  int t = threadIdx.x;
  float s = 0.0f;
  for (int j = t; j < GHS; j += 256){
    if (hkey[j] >= 0){
      float a = (float)harea[j];
      float p = (float)hper[j];
      s += 12.566370614359172f * a / (p * p + 1e-5f);   // 4*pi*A/(P^2+EPS)
    }
  }
  ssum[t] = s;
  __syncthreads();
  for (int w = 128; w > 0; w >>= 1){
    if (t < w) ssum[t] += ssum[t + w];
    __syncthreads();
  }
  if (t == 0){
    float comp = ssum[0] / 64.0f;        // sum(per_label) / D
    out[0] = 1.0f / (comp + 1e-5f);      // 1/(comp + EPS)
  }
}

// ---------------- launcher ----------------
extern "C" void kernel_launch(void* const* d_in, const int* in_sizes, int n_in,
                              void* d_out, int out_size, void* d_ws, size_t ws_size,
                              hipStream_t stream){
  const float* y = (const float*)d_in[0];
  int* parent = (int*)d_ws;           // NN int32 = 16 MiB
  int* hkey   = parent + NN;          // GHS
  int* harea  = hkey + GHS;           // GHS
  int* hper   = harea + GHS;          // GHS
  float* out  = (float*)d_out;

  dim3 blk(256);
  dim3 grd((NN + 255) / 256);         // 16384 blocks
  dim3 grdT(512);                     // 8x8x8 tiles

  hipLaunchKernelGGL(k_local,   grdT, blk, 0, stream, y, parent, hkey, harea, hper);
  hipLaunchKernelGGL(k_cross,   grd,  blk, 0, stream, parent);
  hipLaunchKernelGGL(k_flatten, grd,  blk, 0, stream, parent);
  hipLaunchKernelGGL(k_accum,   grd,  blk, 0, stream, parent, hkey, harea, hper);
  hipLaunchKernelGGL(k_final, dim3(1), blk, 0, stream, hkey, harea, hper, out);
}

// Round 3
// 317.776 us; speedup vs baseline: 2.2851x; 1.9065x over previous
//
#include <hip/hip_runtime.h>

#define DD 64
#define HH 256
#define WW 256
#define NN (DD*HH*WW)   // 4194304
#define GHS 4096        // global hash slots (power of 2)
#define NSEG (NN/32)    // 131072 bitmask words

// tile for local CCL phase
#define TZ 8
#define TY 32
#define TX 32
#define TVOX (TZ*TY*TX) // 8192 -> 32 KB LDS

// backward 26-neighborhood offsets (13)
#define OFFS_LIST \
  {-1,-1,-1},{-1,-1,0},{-1,-1,1}, \
  {-1, 0,-1},{-1, 0,0},{-1, 0,1}, \
  {-1, 1,-1},{-1, 1,0},{-1, 1,1}, \
  { 0,-1,-1},{ 0,-1,0},{ 0,-1,1}, \
  { 0, 0,-1}

// ---------------- union-find with path halving ----------------
// Safety: every write stores an ancestor and preserves P[x] <= x; 4B LDS/global
// accesses are HW-atomic, so concurrent halving stores cannot lose connectivity.
__device__ __forceinline__ int ufind(int* P, int x){
  int p = P[x];
  while (p != x){
    int gp = P[p];
    if (gp != p) P[x] = gp;   // path halving
    x = gp;
    p = P[x];
  }
  return x;
}

__device__ __forceinline__ void uunion(int* P, int a, int b){
  while (true){
    a = ufind(P, a);
    b = ufind(P, b);
    if (a == b) return;
    if (a < b){ int t = a; a = b; b = t; }   // link big -> small
    int old = atomicMin(&P[a], b);
    if (old == a) return;
    a = old;
  }
}

// ---------------- phase A: init + tile-local CCL in LDS + fg bitmask ----------------
__global__ __launch_bounds__(1024) void k_local(const float* __restrict__ in,
                                                int* __restrict__ parent,
                                                unsigned* __restrict__ fgbits,
                                                int* __restrict__ hkey,
                                                int* __restrict__ harea,
                                                int* __restrict__ hper){
  __shared__ int sl[TVOX];
  const int t = threadIdx.x;
  const int b = blockIdx.x;           // 512 tiles: 8 x 8 x 8
  const int z0 = (b >> 6) * TZ;
  const int y0 = ((b >> 3) & 7) * TY;
  const int x0 = (b & 7) * TX;

  if (b < GHS / 1024){ int j = b * 1024 + t; hkey[j] = -1; harea[j] = 0; hper[j] = 0; }

  for (int v = t; v < TVOX; v += 1024){
    int lz = v >> 10, ly = (v >> 5) & 31, lx = v & 31;
    int gi = ((z0 + lz) << 16) | ((y0 + ly) << 8) | (x0 + lx);
    sl[v] = (in[gi] > 0.5f) ? v : -1;
  }
  __syncthreads();

  // fg bitmask: one 32-bit word per (z,y) row segment of this tile.
  // fg-ness (sl[v]>=0) is invariant under unions, so no extra barrier needed.
  if (t < 256){
    int lz = t >> 5, ly = t & 31;
    unsigned m = 0;
    for (int lx = 0; lx < 32; lx++)
      if (sl[(lz << 10) | (ly << 5) | lx] >= 0) m |= (1u << lx);
    fgbits[((z0 + lz) << 11) | ((y0 + ly) << 3) | (x0 >> 5)] = m;
  }

  // local unions over backward neighbors (in-tile only)
  const int offs[13][3] = { OFFS_LIST };
  for (int v = t; v < TVOX; v += 1024){
    if (sl[v] < 0) continue;
    int lz = v >> 10, ly = (v >> 5) & 31, lx = v & 31;
    #pragma unroll
    for (int k = 0; k < 13; k++){
      int zz = lz + offs[k][0];
      int yy = ly + offs[k][1];
      int xx = lx + offs[k][2];
      if (zz < 0 || yy < 0 || yy >= TY || xx < 0 || xx >= TX) continue;
      int u = (zz << 10) | (yy << 5) | xx;
      if (sl[u] >= 0) uunion(sl, v, u);
    }
  }
  __syncthreads();

  // write parent[] with tile-local roots as global indices (min-preserving)
  for (int v = t; v < TVOX; v += 1024){
    int lz = v >> 10, ly = (v >> 5) & 31, lx = v & 31;
    int gi = ((z0 + lz) << 16) | ((y0 + ly) << 8) | (x0 + lx);
    if (sl[v] < 0){ parent[gi] = -1; continue; }
    int r = ufind(sl, v);
    int rz = r >> 10, ry = (r >> 5) & 31, rx = r & 31;
    parent[gi] = ((z0 + rz) << 16) | ((y0 + ry) << 8) | (x0 + rx);
  }
}

// ---------------- phase B: cross-tile unions only ----------------
__global__ void k_cross(int* __restrict__ parent){
  int i = blockIdx.x * blockDim.x + threadIdx.x;
  if (i >= NN) return;
  int x = i & 255, y = (i >> 8) & 255, z = i >> 16;
  int lx = x & 31, ly = y & 31, lz = z & 7;
  if (lz != 0 && ly != 0 && ly != 31 && lx != 0 && lx != 31) return;
  if (parent[i] < 0) return;
  const int offs[13][3] = { OFFS_LIST };
  #pragma unroll
  for (int k = 0; k < 13; k++){
    int zz = z + offs[k][0];
    int yy = y + offs[k][1];
    int xx = x + offs[k][2];
    if (zz < 0 || yy < 0 || yy >= HH || xx < 0 || xx >= WW) continue;
    if ((zz >> 3) == (z >> 3) && (yy >> 5) == (y >> 5) && (xx >> 5) == (x >> 5)) continue;
    int j = (zz << 16) | (yy << 8) | xx;
    if (parent[j] >= 0) uunion(parent, i, j);
  }
}

// ---------------- phase C: bit-parallel 18-neighborhood boundary ----------------
__device__ __forceinline__ int refl(int v, int L){ return v < 0 ? 1 : (v >= L ? L - 2 : v); }

__global__ void k_bnd(const unsigned* __restrict__ fgbits, unsigned* __restrict__ bndbits){
  int seg = blockIdx.x * blockDim.x + threadIdx.x;
  if (seg >= NSEG) return;
  int s = seg & 7, y = (seg >> 3) & 255, z = seg >> 11;
  unsigned own = fgbits[seg];
  if (!own){ bndbits[seg] = 0; return; }
  int zm = refl(z - 1, DD), zp = refl(z + 1, DD);
  int ym = refl(y - 1, HH), yp = refl(y + 1, HH);

  auto row  = [&](int zz, int yy){ return fgbits[(zz << 11) | (yy << 3) | s]; };
  // Lsh: bit b holds fg(x-1); reflect x=-1 -> x=1 at global left edge
  auto rowL = [&](unsigned w, int zz, int yy){
    unsigned c = (s > 0) ? ((fgbits[(zz << 11) | (yy << 3) | (s - 1)] >> 31) & 1u)
                         : ((w >> 1) & 1u);
    return (w << 1) | c;
  };
  // Rsh: bit b holds fg(x+1); reflect x=256 -> x=254 at global right edge
  auto rowR = [&](unsigned w, int zz, int yy){
    unsigned c = (s < 7) ? ((fgbits[(zz << 11) | (yy << 3) | (s + 1)] & 1u) << 31)
                         : ((w & 0x40000000u) << 1);
    return (w >> 1) | c;
  };

  unsigned e = row(zm, ym) & row(zm, yp) & row(zp, ym) & row(zp, yp);   // (±1,±1,0)
  unsigned w;
  w = row(zm, y );  e &= w & rowL(w, zm, y ) & rowR(w, zm, y );          // (-1,0,*)
  w = row(zp, y );  e &= w & rowL(w, zp, y ) & rowR(w, zp, y );          // (+1,0,*)
  w = row(z , ym);  e &= w & rowL(w, z , ym) & rowR(w, z , ym);          // (0,-1,*)
  w = row(z , yp);  e &= w & rowL(w, z , yp) & rowR(w, z , yp);          // (0,+1,*)
  e &= rowL(own, z, y) & rowR(own, z, y);                                // (0,0,±1)
  bndbits[seg] = own & ~e;
}

// ---------------- phase D: roots + wave reduce-by-key + hashed accumulation ----------------
__device__ __forceinline__ void ghash_add(int* hkey, int* harea, int* hper,
                                          int key, int a, int p){
  unsigned h = ((unsigned)key * 2654435761u) >> 20;   // [0,4096)
  while (true){
    int old = atomicCAS(&hkey[h], -1, key);
    if (old == -1 || old == key){
      atomicAdd(&harea[h], a);
      if (p) atomicAdd(&hper[h], p);
      return;
    }
    h = (h + 1) & (GHS - 1);
  }
}

__global__ __launch_bounds__(1024) void k_accum(int* __restrict__ parent,
                                                const unsigned* __restrict__ bndbits,
                                                int* __restrict__ hkey,
                                                int* __restrict__ harea,
                                                int* __restrict__ hper){
  __shared__ int sk[256], sa[256], sp[256];
  const int t = threadIdx.x;
  if (t < 256){ sk[t] = -1; sa[t] = 0; sp[t] = 0; }
  __syncthreads();

  const int i = blockIdx.x * 1024 + t;        // grid exactly covers NN
  int root = -1, bnd = 0;
  if (parent[i] >= 0){
    root = ufind(parent, i);
    int x = i & 255, y = (i >> 8) & 255, z = i >> 16;
    bnd = (bndbits[(z << 11) | (y << 3) | (x >> 5)] >> (x & 31)) & 1;
  }

  // wave-level reduce-by-key over roots
  const int lane = t & 63;
  unsigned long long fgm = __ballot(root >= 0);
  unsigned long long bm  = __ballot(bnd != 0);
  unsigned long long active = fgm;
  while (active){
    int leader = (int)__ffsll((unsigned long long)active) - 1;
    int lroot = __shfl(root, leader);
    unsigned long long match = __ballot(root == lroot) & fgm;
    if (lane == leader){
      int a = (int)__popcll(match);
      int p = (int)__popcll(match & bm);
      // LDS hash insert with bounded probing; spill to global hash if full
      unsigned h = ((unsigned)lroot * 2654435761u) >> 24;
      bool done = false;
      for (int probe = 0; probe < 256; probe++){
        int old = atomicCAS(&sk[h], -1, lroot);
        if (old == -1 || old == lroot){
          atomicAdd(&sa[h], a);
          if (p) atomicAdd(&sp[h], p);
          done = true; break;
        }
        h = (h + 1) & 255;
      }
      if (!done) ghash_add(hkey, harea, hper, lroot, a, p);
    }
    active &= ~match;
  }
  __syncthreads();
  if (t < 256 && sk[t] >= 0) ghash_add(hkey, harea, hper, sk[t], sa[t], sp[t]);
}

// ---------------- phase E: final reduction ----------------
__global__ void k_final(const int* __restrict__ hkey, const int* __restrict__ harea,
                        const int* __restrict__ hper, float* __restrict__ out){
  __shared__ float ssum[256];
  int t = threadIdx.x;
  float s = 0.0f;
  for (int j = t; j < GHS; j += 256){
    if (hkey[j] >= 0){
      float a = (float)harea[j];
      float p = (float)hper[j];
      s += 12.566370614359172f * a / (p * p + 1e-5f);
    }
  }
  ssum[t] = s;
  __syncthreads();
  for (int w = 128; w > 0; w >>= 1){
    if (t < w) ssum[t] += ssum[t + w];
    __syncthreads();
  }
  if (t == 0){
    float comp = ssum[0] / 64.0f;
    out[0] = 1.0f / (comp + 1e-5f);
  }
}

// ---------------- launcher ----------------
extern "C" void kernel_launch(void* const* d_in, const int* in_sizes, int n_in,
                              void* d_out, int out_size, void* d_ws, size_t ws_size,
                              hipStream_t stream){
  const float* y = (const float*)d_in[0];
  int* parent      = (int*)d_ws;            // NN ints = 16 MiB
  int* hkey        = parent + NN;           // GHS
  int* harea       = hkey + GHS;
  int* hper        = harea + GHS;
  unsigned* fgbits = (unsigned*)(hper + GHS);   // NSEG words = 512 KiB
  unsigned* bndbits= fgbits + NSEG;             // NSEG words = 512 KiB
  float* out = (float*)d_out;

  hipLaunchKernelGGL(k_local, dim3(512),   dim3(1024), 0, stream, y, parent, fgbits, hkey, harea, hper);
  hipLaunchKernelGGL(k_cross, dim3(NN/256),dim3(256),  0, stream, parent);
  hipLaunchKernelGGL(k_bnd,   dim3(NSEG/256), dim3(256), 0, stream, fgbits, bndbits);
  hipLaunchKernelGGL(k_accum, dim3(NN/1024), dim3(1024), 0, stream, parent, bndbits, hkey, harea, hper);
  hipLaunchKernelGGL(k_final, dim3(1),     dim3(256),  0, stream, hkey, harea, hper, out);
}

// Round 4
// 314.675 us; speedup vs baseline: 2.3076x; 1.0099x over previous
//
#include <hip/hip_runtime.h>

#define DD 64
#define HH 256
#define WW 256
#define NN (DD*HH*WW)   // 4194304
#define GHS 4096        // global stats-hash slots (power of 2)
#define PHS 131072      // global pair-hash slots (power of 2, 64-bit keys)
#define NSEG (NN/32)    // 131072 bitmask words

// tile for local CCL phase
#define TZ 8
#define TY 32
#define TX 32
#define TVOX (TZ*TY*TX) // 8192 -> 32 KB LDS

// backward 26-neighborhood offsets (13)
#define OFFS_LIST \
  {-1,-1,-1},{-1,-1,0},{-1,-1,1}, \
  {-1, 0,-1},{-1, 0,0},{-1, 0,1}, \
  {-1, 1,-1},{-1, 1,0},{-1, 1,1}, \
  { 0,-1,-1},{ 0,-1,0},{ 0,-1,1}, \
  { 0, 0,-1}

// ---------------- union-find with path halving ----------------
// Safety: every write stores an ancestor and preserves P[x] <= x; 4B accesses
// are HW-atomic, so concurrent halving stores cannot lose connectivity.
__device__ __forceinline__ int ufind(int* P, int x){
  int p = P[x];
  while (p != x){
    int gp = P[p];
    if (gp != p) P[x] = gp;   // path halving
    x = gp;
    p = P[x];
  }
  return x;
}

__device__ __forceinline__ void uunion(int* P, int a, int b){
  while (true){
    a = ufind(P, a);
    b = ufind(P, b);
    if (a == b) return;
    if (a < b){ int t = a; a = b; b = t; }   // link big -> small
    int old = atomicMin(&P[a], b);
    if (old == a) return;
    a = old;
  }
}

// ---------------- phase A: init + tile-local CCL in LDS + fg bitmask ----------------
__global__ __launch_bounds__(1024) void k_local(const float* __restrict__ in,
                                                int* __restrict__ parent,
                                                unsigned* __restrict__ fgbits,
                                                int* __restrict__ hkey,
                                                int* __restrict__ harea,
                                                int* __restrict__ hper,
                                                unsigned long long* __restrict__ ph){
  __shared__ int sl[TVOX];
  const int t = threadIdx.x;
  const int b = blockIdx.x;           // 512 tiles: 8 x 8 x 8
  const int z0 = (b >> 6) * TZ;
  const int y0 = ((b >> 3) & 7) * TY;
  const int x0 = (b & 7) * TX;

  if (b < GHS / 1024){ int j = b * 1024 + t; hkey[j] = -1; harea[j] = 0; hper[j] = 0; }
  { int j = b * 1024 + t; if (j < PHS) ph[j] = ~0ULL; }   // pair hash sentinel

  for (int v = t; v < TVOX; v += 1024){
    int lz = v >> 10, ly = (v >> 5) & 31, lx = v & 31;
    int gi = ((z0 + lz) << 16) | ((y0 + ly) << 8) | (x0 + lx);
    sl[v] = (in[gi] > 0.5f) ? v : -1;
  }
  __syncthreads();

  // fg bitmask: one word per (z,y) row of this tile (fg-ness invariant under unions)
  if (t < 256){
    int lz = t >> 5, ly = t & 31;
    unsigned m = 0;
    for (int lx = 0; lx < 32; lx++)
      if (sl[(lz << 10) | (ly << 5) | lx] >= 0) m |= (1u << lx);
    fgbits[((z0 + lz) << 11) | ((y0 + ly) << 3) | (x0 >> 5)] = m;
  }

  // local unions over backward neighbors (in-tile only)
  const int offs[13][3] = { OFFS_LIST };
  for (int v = t; v < TVOX; v += 1024){
    if (sl[v] < 0) continue;
    int lz = v >> 10, ly = (v >> 5) & 31, lx = v & 31;
    #pragma unroll
    for (int k = 0; k < 13; k++){
      int zz = lz + offs[k][0];
      int yy = ly + offs[k][1];
      int xx = lx + offs[k][2];
      if (zz < 0 || yy < 0 || yy >= TY || xx < 0 || xx >= TX) continue;
      int u = (zz << 10) | (yy << 5) | xx;
      if (sl[u] >= 0) uunion(sl, v, u);
    }
  }
  __syncthreads();

  // write parent[] with tile-local roots as global indices (min-preserving)
  for (int v = t; v < TVOX; v += 1024){
    int lz = v >> 10, ly = (v >> 5) & 31, lx = v & 31;
    int gi = ((z0 + lz) << 16) | ((y0 + ly) << 8) | (x0 + lx);
    if (sl[v] < 0){ parent[gi] = -1; continue; }
    int r = ufind(sl, v);
    int rz = r >> 10, ry = (r >> 5) & 31, rx = r & 31;
    parent[gi] = ((z0 + rz) << 16) | ((y0 + ry) << 8) | (x0 + rx);
  }
}

// ---------------- phase B1: collect distinct cross-tile label pairs ----------------
__device__ __forceinline__ void phash_insert(unsigned long long* H, unsigned long long key){
  unsigned h = (unsigned)((key * 0x9E3779B97F4A7C15ull) >> 47);   // [0, 2^17)
  while (true){
    unsigned long long old = atomicCAS(&H[h], ~0ULL, key);
    if (old == ~0ULL || old == key) return;
    h = (h + 1) & (PHS - 1);
  }
}

__global__ __launch_bounds__(256) void k_pairs(const int* __restrict__ parent,
                                               unsigned long long* __restrict__ ph){
  const int i = blockIdx.x * 256 + threadIdx.x;
  const int x = i & 255, y = (i >> 8) & 255, z = i >> 16;
  const int lx = x & 31, ly = y & 31, lz = z & 7;
  const bool bvox = (lz == 0) | (ly == 0) | (ly == 31) | (lx == 0) | (lx == 31);
  int a = -1;
  if (bvox) a = parent[i];                 // phase-A tile root (stable; read-only pass)
  const int offs[13][3] = { OFFS_LIST };
  const int lane = threadIdx.x & 63;
  #pragma unroll
  for (int k = 0; k < 13; k++){
    int zz = z + offs[k][0], yy = y + offs[k][1], xx = x + offs[k][2];
    bool v = (a >= 0) && zz >= 0 && yy >= 0 && yy < HH && xx >= 0 && xx < WW &&
             !((zz >> 3) == (z >> 3) && (yy >> 5) == (y >> 5) && (xx >> 5) == (x >> 5));
    int bl = -1;
    if (v) bl = parent[(zz << 16) | (yy << 8) | xx];
    v = v && (bl >= 0);
    int hi = a > bl ? a : bl, lo = a > bl ? bl : a;
    unsigned long long key = v ? (((unsigned long long)(unsigned)hi << 32) | (unsigned)lo) : ~0ULL;
    unsigned long long act = __ballot(v);
    while (act){
      int leader = (int)__ffsll(act) - 1;
      int khi = __shfl((int)(key >> 32), leader);
      int klo = __shfl((int)key, leader);
      unsigned long long lkey = ((unsigned long long)(unsigned)khi << 32) | (unsigned)klo;
      unsigned long long m = __ballot(v && key == lkey);
      if (lane == leader) phash_insert(ph, key);
      act &= ~m;
    }
  }
}

// ---------------- phase B2: union distinct pairs only ----------------
__global__ __launch_bounds__(256) void k_union(const unsigned long long* __restrict__ ph,
                                               int* __restrict__ parent){
  int s = blockIdx.x * 256 + threadIdx.x;     // grid covers PHS
  unsigned long long key = ph[s];
  if (key == ~0ULL) return;
  int a = (int)(key >> 32);
  int b = (int)(key & 0xffffffffu);
  uunion(parent, a, b);
}

// ---------------- phase C: bit-parallel 18-neighborhood boundary ----------------
__device__ __forceinline__ int refl(int v, int L){ return v < 0 ? 1 : (v >= L ? L - 2 : v); }

__global__ void k_bnd(const unsigned* __restrict__ fgbits, unsigned* __restrict__ bndbits){
  int seg = blockIdx.x * blockDim.x + threadIdx.x;
  if (seg >= NSEG) return;
  int s = seg & 7, y = (seg >> 3) & 255, z = seg >> 11;
  unsigned own = fgbits[seg];
  if (!own){ bndbits[seg] = 0; return; }
  int zm = refl(z - 1, DD), zp = refl(z + 1, DD);
  int ym = refl(y - 1, HH), yp = refl(y + 1, HH);

  auto row  = [&](int zz, int yy){ return fgbits[(zz << 11) | (yy << 3) | s]; };
  auto rowL = [&](unsigned w, int zz, int yy){
    unsigned c = (s > 0) ? ((fgbits[(zz << 11) | (yy << 3) | (s - 1)] >> 31) & 1u)
                         : ((w >> 1) & 1u);
    return (w << 1) | c;
  };
  auto rowR = [&](unsigned w, int zz, int yy){
    unsigned c = (s < 7) ? ((fgbits[(zz << 11) | (yy << 3) | (s + 1)] & 1u) << 31)
                         : ((w & 0x40000000u) << 1);
    return (w >> 1) | c;
  };

  unsigned e = row(zm, ym) & row(zm, yp) & row(zp, ym) & row(zp, yp);   // (±1,±1,0)
  unsigned w;
  w = row(zm, y );  e &= w & rowL(w, zm, y ) & rowR(w, zm, y );          // (-1,0,*)
  w = row(zp, y );  e &= w & rowL(w, zp, y ) & rowR(w, zp, y );          // (+1,0,*)
  w = row(z , ym);  e &= w & rowL(w, z , ym) & rowR(w, z , ym);          // (0,-1,*)
  w = row(z , yp);  e &= w & rowL(w, z , yp) & rowR(w, z , yp);          // (0,+1,*)
  e &= rowL(own, z, y) & rowR(own, z, y);                                // (0,0,±1)
  bndbits[seg] = own & ~e;
}

// ---------------- phase D: wave reduce-by-key, find only per distinct label ----------------
__device__ __forceinline__ void ghash_add(int* hkey, int* harea, int* hper,
                                          int key, int a, int p){
  unsigned h = ((unsigned)key * 2654435761u) >> 20;   // [0,4096)
  while (true){
    int old = atomicCAS(&hkey[h], -1, key);
    if (old == -1 || old == key){
      atomicAdd(&harea[h], a);
      if (p) atomicAdd(&hper[h], p);
      return;
    }
    h = (h + 1) & (GHS - 1);
  }
}

__global__ __launch_bounds__(1024) void k_accum(int* __restrict__ parent,
                                                const unsigned* __restrict__ bndbits,
                                                int* __restrict__ hkey,
                                                int* __restrict__ harea,
                                                int* __restrict__ hper){
  __shared__ int sk[256], sa[256], sp[256];
  const int t = threadIdx.x;
  if (t < 256){ sk[t] = -1; sa[t] = 0; sp[t] = 0; }
  __syncthreads();

  const int i = blockIdx.x * 1024 + t;        // grid exactly covers NN
  int lab = parent[i];                        // raw label (tile root); -1 = bg
  int bnd = 0;
  if (lab >= 0){
    int x = i & 255, y = (i >> 8) & 255, z = i >> 16;
    bnd = (bndbits[(z << 11) | (y << 3) | (x >> 5)] >> (x & 31)) & 1;
  }

  // wave-level reduce-by-key over RAW labels; leaders do the (expensive) find
  const int lane = t & 63;
  unsigned long long fgm = __ballot(lab >= 0);
  unsigned long long bm  = __ballot(bnd != 0);
  unsigned long long act = fgm;
  while (act){
    int leader = (int)__ffsll(act) - 1;
    int llab = __shfl(lab, leader);
    unsigned long long match = __ballot(lab == llab) & fgm;
    if (lane == leader){
      int r = ufind(parent, llab);            // one find per distinct raw label
      int a = (int)__popcll(match);
      int p = (int)__popcll(match & bm);
      unsigned h = ((unsigned)r * 2654435761u) >> 24;
      bool done = false;
      for (int probe = 0; probe < 256; probe++){
        int old = atomicCAS(&sk[h], -1, r);
        if (old == -1 || old == r){
          atomicAdd(&sa[h], a);
          if (p) atomicAdd(&sp[h], p);
          done = true; break;
        }
        h = (h + 1) & 255;
      }
      if (!done) ghash_add(hkey, harea, hper, r, a, p);
    }
    act &= ~match;
  }
  __syncthreads();
  if (t < 256 && sk[t] >= 0) ghash_add(hkey, harea, hper, sk[t], sa[t], sp[t]);
}

// ---------------- phase E: final reduction ----------------
__global__ void k_final(const int* __restrict__ hkey, const int* __restrict__ harea,
                        const int* __restrict__ hper, float* __restrict__ out){
  __shared__ float ssum[256];
  int t = threadIdx.x;
  float s = 0.0f;
  for (int j = t; j < GHS; j += 256){
    if (hkey[j] >= 0){
      float a = (float)harea[j];
      float p = (float)hper[j];
      s += 12.566370614359172f * a / (p * p + 1e-5f);
    }
  }
  ssum[t] = s;
  __syncthreads();
  for (int w = 128; w > 0; w >>= 1){
    if (t < w) ssum[t] += ssum[t + w];
    __syncthreads();
  }
  if (t == 0){
    float comp = ssum[0] / 64.0f;
    out[0] = 1.0f / (comp + 1e-5f);
  }
}

// ---------------- launcher ----------------
extern "C" void kernel_launch(void* const* d_in, const int* in_sizes, int n_in,
                              void* d_out, int out_size, void* d_ws, size_t ws_size,
                              hipStream_t stream){
  const float* y = (const float*)d_in[0];
  char* w = (char*)d_ws;
  int* parent            = (int*)w;                    w += (size_t)NN * 4;      // 16 MiB
  unsigned long long* ph = (unsigned long long*)w;     w += (size_t)PHS * 8;     // 1 MiB
  int* hkey              = (int*)w;                    w += GHS * 4;
  int* harea             = (int*)w;                    w += GHS * 4;
  int* hper              = (int*)w;                    w += GHS * 4;
  unsigned* fgbits       = (unsigned*)w;               w += (size_t)NSEG * 4;    // 512 KiB
  unsigned* bndbits      = (unsigned*)w;               w += (size_t)NSEG * 4;    // 512 KiB
  float* out = (float*)d_out;

  hipLaunchKernelGGL(k_local, dim3(512),      dim3(1024), 0, stream, y, parent, fgbits, hkey, harea, hper, ph);
  hipLaunchKernelGGL(k_pairs, dim3(NN/256),   dim3(256),  0, stream, parent, ph);
  hipLaunchKernelGGL(k_union, dim3(PHS/256),  dim3(256),  0, stream, ph, parent);
  hipLaunchKernelGGL(k_bnd,   dim3(NSEG/256), dim3(256),  0, stream, fgbits, bndbits);
  hipLaunchKernelGGL(k_accum, dim3(NN/1024),  dim3(1024), 0, stream, parent, bndbits, hkey, harea, hper);
  hipLaunchKernelGGL(k_final, dim3(1),        dim3(256),  0, stream, hkey, harea, hper, out);
}

// Round 5
// 256.767 us; speedup vs baseline: 2.8280x; 1.2255x over previous
//
#include <hip/hip_runtime.h>

#define DD 64
#define HH 256
#define WW 256
#define NN (DD*HH*WW)   // 4194304
#define GHS 4096        // global stats-hash slots (power of 2)
#define PHS 131072      // global pair-hash slots (power of 2, 64-bit keys)
#define NSEG (NN/32)    // 131072 bitmask words

// tile for local CCL phase
#define TZ 8
#define TY 32
#define TX 32
#define TVOX (TZ*TY*TX) // 8192 -> 32 KB LDS

// backward 26-neighborhood offsets (13)
#define OFFS_LIST \
  {-1,-1,-1},{-1,-1,0},{-1,-1,1}, \
  {-1, 0,-1},{-1, 0,0},{-1, 0,1}, \
  {-1, 1,-1},{-1, 1,0},{-1, 1,1}, \
  { 0,-1,-1},{ 0,-1,0},{ 0,-1,1}, \
  { 0, 0,-1}

// ---------------- union-find with path halving ----------------
// Safety: every write stores an ancestor and preserves P[x] <= x; 4B accesses
// are HW-atomic, so concurrent halving stores cannot lose connectivity.
__device__ __forceinline__ int ufind(int* P, int x){
  int p = P[x];
  while (p != x){
    int gp = P[p];
    if (gp != p) P[x] = gp;   // path halving
    x = gp;
    p = P[x];
  }
  return x;
}

__device__ __forceinline__ void uunion(int* P, int a, int b){
  while (true){
    a = ufind(P, a);
    b = ufind(P, b);
    if (a == b) return;
    if (a < b){ int t = a; a = b; b = t; }   // link big -> small
    int old = atomicMin(&P[a], b);
    if (old == a) return;
    a = old;
  }
}

// ---------------- phase A: run-based tile-local CCL in LDS ----------------
__global__ __launch_bounds__(1024) void k_local(const float* __restrict__ in,
                                                int* __restrict__ parent,
                                                unsigned* __restrict__ fgbits,
                                                int* __restrict__ hkey,
                                                int* __restrict__ harea,
                                                int* __restrict__ hper,
                                                unsigned long long* __restrict__ ph){
  __shared__ int sl[TVOX];
  __shared__ unsigned srow[256];      // fg mask per (lz,ly) row of the tile
  const int t = threadIdx.x;
  const int b = blockIdx.x;           // 512 tiles: 8 x 8 x 8
  const int z0 = (b >> 6) * TZ;
  const int y0 = ((b >> 3) & 7) * TY;
  const int x0 = (b & 7) * TX;

  if (b < GHS / 1024){ int j = b * 1024 + t; hkey[j] = -1; harea[j] = 0; hper[j] = 0; }
  { int j = b * 1024 + t; if (j < PHS) ph[j] = ~0ULL; }   // pair hash sentinel

  // A1: build row fg-masks via wave ballot (rows are 32 voxels = half a wave)
  const int lane = t & 63;
  #pragma unroll
  for (int k = 0; k < 8; k++){
    int v = t + k * 1024;
    int lz = v >> 10, ly = (v >> 5) & 31, lx = v & 31;
    int gi = ((z0 + lz) << 16) | ((y0 + ly) << 8) | (x0 + lx);
    bool fg = in[gi] > 0.5f;
    unsigned long long m = __ballot(fg);
    int row = v >> 5;                 // this thread's own row
    if (lane == 0)       srow[row] = (unsigned)m;          // low word = this row
    else if (lane == 32) srow[row] = (unsigned)(m >> 32);  // high word = its row
  }
  __syncthreads();

  // A2: fgbits store + run-start label init (label = index of x-run start)
  if (t < 256)
    fgbits[((z0 + (t >> 5)) << 11) | ((y0 + (t & 31)) << 3) | (x0 >> 5)] = srow[t];
  #pragma unroll
  for (int k = 0; k < 8; k++){
    int v = t + k * 1024;
    int row = v >> 5, x = v & 31;
    unsigned m = srow[row];
    int lab = -1;
    if ((m >> x) & 1){
      unsigned u = (~m) & ((x == 0) ? 0u : ((1u << x) - 1u));  // zeros below x
      int start = (u == 0) ? 0 : (32 - __builtin_clz(u));
      lab = (row << 5) | start;
    }
    sl[v] = lab;
  }
  __syncthreads();

  // A3: unions over 4 backward row-relations; skip x+-1 when bit x is set
  // (contiguous bits = same run = same label, union redundant).
  const int rel[4][2] = {{-1,-1},{-1,0},{-1,1},{0,-1}};   // (dz,dy)
  #pragma unroll
  for (int k = 0; k < 8; k++){
    int v = t + k * 1024;
    int row = v >> 5, x = v & 31;
    if (!((srow[row] >> x) & 1)) continue;
    int lz = row >> 5, ly = row & 31;
    #pragma unroll
    for (int r = 0; r < 4; r++){
      int zz = lz + rel[r][0], yy = ly + rel[r][1];
      if (zz < 0 || yy < 0 || yy >= TY) continue;
      int nrow = (zz << 5) | yy;
      unsigned mR = srow[nrow];
      if ((mR >> x) & 1) uunion(sl, v, (nrow << 5) | x);
      else {
        if (x > 0  && ((mR >> (x - 1)) & 1)) uunion(sl, v, (nrow << 5) | (x - 1));
        if (x < 31 && ((mR >> (x + 1)) & 1)) uunion(sl, v, (nrow << 5) | (x + 1));
      }
    }
  }
  __syncthreads();

  // A4: write parent[] with tile-local roots as global indices (min-preserving)
  #pragma unroll
  for (int k = 0; k < 8; k++){
    int v = t + k * 1024;
    int lz = v >> 10, ly = (v >> 5) & 31, lx = v & 31;
    int gi = ((z0 + lz) << 16) | ((y0 + ly) << 8) | (x0 + lx);
    if (sl[v] < 0){ parent[gi] = -1; continue; }
    int r = ufind(sl, v);
    int rz = r >> 10, ry = (r >> 5) & 31, rx = r & 31;
    parent[gi] = ((z0 + rz) << 16) | ((y0 + ry) << 8) | (x0 + rx);
  }
}

// ---------------- phase B1: collect distinct cross-tile label pairs ----------------
__device__ __forceinline__ void phash_insert(unsigned long long* H, unsigned long long key){
  unsigned h = (unsigned)((key * 0x9E3779B97F4A7C15ull) >> 47);   // [0, 2^17)
  while (true){
    unsigned long long old = atomicCAS(&H[h], ~0ULL, key);
    if (old == ~0ULL || old == key) return;
    h = (h + 1) & (PHS - 1);
  }
}

__global__ __launch_bounds__(256) void k_pairs(const int* __restrict__ parent,
                                               unsigned long long* __restrict__ ph){
  __shared__ unsigned long long pk[256];    // per-block pair-dedup hash
  const int t = threadIdx.x;
  pk[t] = ~0ULL;
  __syncthreads();

  const int i = blockIdx.x * 256 + t;
  const int x = i & 255, y = (i >> 8) & 255, z = i >> 16;
  const int lx = x & 31, ly = y & 31, lz = z & 7;
  const bool bvox = (lz == 0) | (ly == 0) | (ly == 31) | (lx == 0) | (lx == 31);
  int a = bvox ? parent[i] : -1;            // phase-A tile root (read-only pass)
  if (a >= 0){
    const int offs[13][3] = { OFFS_LIST };
    #pragma unroll
    for (int k = 0; k < 13; k++){
      int zz = z + offs[k][0], yy = y + offs[k][1], xx = x + offs[k][2];
      if (zz < 0 || yy < 0 || yy >= HH || xx < 0 || xx >= WW) continue;
      if ((zz >> 3) == (z >> 3) && (yy >> 5) == (y >> 5) && (xx >> 5) == (x >> 5)) continue;
      int bl = parent[(zz << 16) | (yy << 8) | xx];
      if (bl < 0) continue;
      int hi = a > bl ? a : bl, lo = a > bl ? bl : a;
      unsigned long long key = ((unsigned long long)(unsigned)hi << 32) | (unsigned)lo;
      unsigned h = (unsigned)((key * 0x9E3779B97F4A7C15ull) >> 56);  // [0,256)
      bool done = false;
      for (int probe = 0; probe < 256; probe++){
        unsigned long long old = atomicCAS(&pk[h], ~0ULL, key);
        if (old == ~0ULL || old == key){ done = true; break; }
        h = (h + 1) & 255;
      }
      if (!done) phash_insert(ph, key);     // LDS hash full -> global
    }
  }
  __syncthreads();
  if (pk[t] != ~0ULL) phash_insert(ph, pk[t]);
}

// ---------------- phase B2: union distinct pairs only ----------------
__global__ __launch_bounds__(256) void k_union(const unsigned long long* __restrict__ ph,
                                               int* __restrict__ parent){
  int s = blockIdx.x * 256 + threadIdx.x;     // grid covers PHS
  unsigned long long key = ph[s];
  if (key == ~0ULL) return;
  int a = (int)(key >> 32);
  int b = (int)(key & 0xffffffffu);
  uunion(parent, a, b);
}

// ---------------- phase C: bit-parallel 18-neighborhood boundary ----------------
__device__ __forceinline__ int refl(int v, int L){ return v < 0 ? 1 : (v >= L ? L - 2 : v); }

__global__ void k_bnd(const unsigned* __restrict__ fgbits, unsigned* __restrict__ bndbits){
  int seg = blockIdx.x * blockDim.x + threadIdx.x;
  if (seg >= NSEG) return;
  int s = seg & 7, y = (seg >> 3) & 255, z = seg >> 11;
  unsigned own = fgbits[seg];
  if (!own){ bndbits[seg] = 0; return; }
  int zm = refl(z - 1, DD), zp = refl(z + 1, DD);
  int ym = refl(y - 1, HH), yp = refl(y + 1, HH);

  auto row  = [&](int zz, int yy){ return fgbits[(zz << 11) | (yy << 3) | s]; };
  auto rowL = [&](unsigned w, int zz, int yy){
    unsigned c = (s > 0) ? ((fgbits[(zz << 11) | (yy << 3) | (s - 1)] >> 31) & 1u)
                         : ((w >> 1) & 1u);
    return (w << 1) | c;
  };
  auto rowR = [&](unsigned w, int zz, int yy){
    unsigned c = (s < 7) ? ((fgbits[(zz << 11) | (yy << 3) | (s + 1)] & 1u) << 31)
                         : ((w & 0x40000000u) << 1);
    return (w >> 1) | c;
  };

  unsigned e = row(zm, ym) & row(zm, yp) & row(zp, ym) & row(zp, yp);   // (±1,±1,0)
  unsigned w;
  w = row(zm, y );  e &= w & rowL(w, zm, y ) & rowR(w, zm, y );          // (-1,0,*)
  w = row(zp, y );  e &= w & rowL(w, zp, y ) & rowR(w, zp, y );          // (+1,0,*)
  w = row(z , ym);  e &= w & rowL(w, z , ym) & rowR(w, z , ym);          // (0,-1,*)
  w = row(z , yp);  e &= w & rowL(w, z , yp) & rowR(w, z , yp);          // (0,+1,*)
  e &= rowL(own, z, y) & rowR(own, z, y);                                // (0,0,±1)
  bndbits[seg] = own & ~e;
}

// ---------------- phase D: wave reduce-by-key, find only per distinct label ----------------
__device__ __forceinline__ void ghash_add(int* hkey, int* harea, int* hper,
                                          int key, int a, int p){
  unsigned h = ((unsigned)key * 2654435761u) >> 20;   // [0,4096)
  while (true){
    int old = atomicCAS(&hkey[h], -1, key);
    if (old == -1 || old == key){
      atomicAdd(&harea[h], a);
      if (p) atomicAdd(&hper[h], p);
      return;
    }
    h = (h + 1) & (GHS - 1);
  }
}

__global__ __launch_bounds__(1024) void k_accum(int* __restrict__ parent,
                                                const unsigned* __restrict__ bndbits,
                                                int* __restrict__ hkey,
                                                int* __restrict__ harea,
                                                int* __restrict__ hper){
  __shared__ int sk[256], sa[256], sp[256];
  const int t = threadIdx.x;
  if (t < 256){ sk[t] = -1; sa[t] = 0; sp[t] = 0; }
  __syncthreads();

  const int i = blockIdx.x * 1024 + t;        // grid exactly covers NN
  int lab = parent[i];                        // raw label (tile root); -1 = bg
  int bnd = 0;
  if (lab >= 0){
    int x = i & 255, y = (i >> 8) & 255, z = i >> 16;
    bnd = (bndbits[(z << 11) | (y << 3) | (x >> 5)] >> (x & 31)) & 1;
  }

  const int lane = t & 63;
  unsigned long long fgm = __ballot(lab >= 0);
  unsigned long long bm  = __ballot(bnd != 0);
  unsigned long long act = fgm;
  while (act){
    int leader = (int)__ffsll(act) - 1;
    int llab = __shfl(lab, leader);
    unsigned long long match = __ballot(lab == llab) & fgm;
    if (lane == leader){
      int r = ufind(parent, llab);            // one find per distinct raw label
      int a = (int)__popcll(match);
      int p = (int)__popcll(match & bm);
      unsigned h = ((unsigned)r * 2654435761u) >> 24;
      bool done = false;
      for (int probe = 0; probe < 256; probe++){
        int old = atomicCAS(&sk[h], -1, r);
        if (old == -1 || old == r){
          atomicAdd(&sa[h], a);
          if (p) atomicAdd(&sp[h], p);
          done = true; break;
        }
        h = (h + 1) & 255;
      }
      if (!done) ghash_add(hkey, harea, hper, r, a, p);
    }
    act &= ~match;
  }
  __syncthreads();
  if (t < 256 && sk[t] >= 0) ghash_add(hkey, harea, hper, sk[t], sa[t], sp[t]);
}

// ---------------- phase E: final reduction ----------------
__global__ void k_final(const int* __restrict__ hkey, const int* __restrict__ harea,
                        const int* __restrict__ hper, float* __restrict__ out){
  __shared__ float ssum[256];
  int t = threadIdx.x;
  float s = 0.0f;
  for (int j = t; j < GHS; j += 256){
    if (hkey[j] >= 0){
      float a = (float)harea[j];
      float p = (float)hper[j];
      s += 12.566370614359172f * a / (p * p + 1e-5f);
    }
  }
  ssum[t] = s;
  __syncthreads();
  for (int w = 128; w > 0; w >>= 1){
    if (t < w) ssum[t] += ssum[t + w];
    __syncthreads();
  }
  if (t == 0){
    float comp = ssum[0] / 64.0f;
    out[0] = 1.0f / (comp + 1e-5f);
  }
}

// ---------------- launcher ----------------
extern "C" void kernel_launch(void* const* d_in, const int* in_sizes, int n_in,
                              void* d_out, int out_size, void* d_ws, size_t ws_size,
                              hipStream_t stream){
  const float* y = (const float*)d_in[0];
  char* w = (char*)d_ws;
  int* parent            = (int*)w;                    w += (size_t)NN * 4;      // 16 MiB
  unsigned long long* ph = (unsigned long long*)w;     w += (size_t)PHS * 8;     // 1 MiB
  int* hkey              = (int*)w;                    w += GHS * 4;
  int* harea             = (int*)w;                    w += GHS * 4;
  int* hper              = (int*)w;                    w += GHS * 4;
  unsigned* fgbits       = (unsigned*)w;               w += (size_t)NSEG * 4;    // 512 KiB
  unsigned* bndbits      = (unsigned*)w;               w += (size_t)NSEG * 4;    // 512 KiB
  float* out = (float*)d_out;

  hipLaunchKernelGGL(k_local, dim3(512),      dim3(1024), 0, stream, y, parent, fgbits, hkey, harea, hper, ph);
  hipLaunchKernelGGL(k_pairs, dim3(NN/256),   dim3(256),  0, stream, parent, ph);
  hipLaunchKernelGGL(k_union, dim3(PHS/256),  dim3(256),  0, stream, ph, parent);
  hipLaunchKernelGGL(k_bnd,   dim3(NSEG/256), dim3(256),  0, stream, fgbits, bndbits);
  hipLaunchKernelGGL(k_accum, dim3(NN/1024),  dim3(1024), 0, stream, parent, bndbits, hkey, harea, hper);
  hipLaunchKernelGGL(k_final, dim3(1),        dim3(256),  0, stream, hkey, harea, hper, out);
}